// Round 1
// baseline (1889.875 us; speedup 1.0000x reference)
//
#include <hip/hip_runtime.h>
#include <hip/hip_bf16.h>

typedef __attribute__((ext_vector_type(4))) float f32x4;
typedef __attribute__((ext_vector_type(8))) short short8;
typedef __attribute__((ext_vector_type(8))) unsigned short ushort8;
typedef float f4a __attribute__((ext_vector_type(4), aligned(4)));  // unaligned-tolerant float4

__device__ __forceinline__ unsigned short f2bf(float f) {
  unsigned int u = __float_as_uint(f);
  u += 0x7fffu + ((u >> 16) & 1u);   // RNE (finite inputs only)
  return (unsigned short)(u >> 16);
}

// ---------------- build xh = [emb[X], h] as bf16 [2048][4096] ----------------
__global__ __launch_bounds__(256) void k_build_xh(
    const int* __restrict__ X, const float* __restrict__ h,
    const float* __restrict__ emb, unsigned short* __restrict__ xh) {
  int b = blockIdx.x;
  int tid = threadIdx.x;
  int j0 = tid * 16;   // 256 threads * 16 cols = 4096
  const float* src;
  if (j0 < 2048) {
    int xb = X[b];
    src = emb + (size_t)xb * 2048 + j0;
  } else {
    src = h + (size_t)b * 2048 + (j0 - 2048);
  }
  unsigned short* dst = xh + (size_t)b * 4096 + j0;
#pragma unroll
  for (int half = 0; half < 2; ++half) {
    float4 f0 = *(const float4*)(src + half * 8);
    float4 f1 = *(const float4*)(src + half * 8 + 4);
    ushort8 o;
    o[0] = f2bf(f0.x); o[1] = f2bf(f0.y); o[2] = f2bf(f0.z); o[3] = f2bf(f0.w);
    o[4] = f2bf(f1.x); o[5] = f2bf(f1.y); o[6] = f2bf(f1.z); o[7] = f2bf(f1.w);
    *(ushort8*)(dst + half * 8) = o;
  }
}

// ---------------- unified GEMM: C[M][N] = A(bf16)[M][K] @ concat(B0..B3)(f32) ----------------
// B parts are each [K][part_cols] f32 row-major; virtual B = concat along columns.
// m97-style: 128x128 tile, BK=32, 4 waves of 64x64, mfma_f32_16x16x32_bf16.
struct BParts { const float* p0; const float* p1; const float* p2; const float* p3; };

__global__ __launch_bounds__(256) void k_gemm(
    const unsigned short* __restrict__ A, BParts bp, int part_cols,
    const float* __restrict__ bias, float* __restrict__ C,
    int N, int K, int lda) {
  __shared__ unsigned short As[128 * 32];   // [row][32] linear (global_load_lds dest)
  __shared__ unsigned short Bt[128 * 40];   // [col][40] padded (stride 80B, 16B-aligned)

  const int tid = threadIdx.x;
  const int lane = tid & 63;
  const int wid = tid >> 6;
  const int mrow0 = blockIdx.y * 128;
  const int ncol0 = blockIdx.x * 128;

  // tile lies fully within one B part (part_cols % 128 == 0, or single part)
  const int p = ncol0 / part_cols;
  const float* Bp = (p == 0) ? bp.p0 : (p == 1) ? bp.p1 : (p == 2) ? bp.p2 : bp.p3;
  const int ncol_in_part = ncol0 - p * part_cols;
  const bool full = (ncol0 + 128 <= N);

  // B staging mapping: thread -> k-pair (2 rows) x 8 cols
  const int kp = tid >> 4;   // 0..15 -> k = 2*kp, 2*kp+1
  const int cg = tid & 15;   // cols cg*8 .. cg*8+7

  f32x4 acc[4][4];
#pragma unroll
  for (int m = 0; m < 4; ++m)
#pragma unroll
    for (int n = 0; n < 4; ++n) acc[m][n] = {0.f, 0.f, 0.f, 0.f};

  const int wr = wid >> 1, wc = wid & 1;
  const int brow0 = wr * 64, bcol0 = wc * 64;

  int a_off[4], b_off[4];
#pragma unroll
  for (int m = 0; m < 4; ++m)
    a_off[m] = (brow0 + m * 16 + (lane & 15)) * 32 + ((lane >> 4) << 3);
#pragma unroll
  for (int n = 0; n < 4; ++n)
    b_off[n] = (bcol0 + n * 16 + (lane & 15)) * 40 + ((lane >> 4) << 3);

  for (int k0 = 0; k0 < K; k0 += 32) {
    // ---- stage A: 8KB via global_load_lds width=16 (512 slots, 2/thread)
#pragma unroll
    for (int i = 0; i < 2; ++i) {
      int t = i * 256 + wid * 64 + lane;       // slot
      int r = t >> 2, ck = t & 3;
      const unsigned short* g = A + (size_t)(mrow0 + r) * lda + k0 + ck * 8;
      unsigned short* ldsdst = As + (size_t)(i * 256 + wid * 64) * 8;  // wave-uniform base
      __builtin_amdgcn_global_load_lds(
          (const __attribute__((address_space(1))) void*)g,
          (__attribute__((address_space(3))) void*)ldsdst, 16, 0, 0);
    }
    // ---- stage B: f32 -> bf16, transposed into Bt[col][k]
    {
      int krow = k0 + kp * 2;
      const float* r0 = Bp + (size_t)krow * part_cols + ncol_in_part + cg * 8;
      const float* r1 = r0 + part_cols;
      float v0[8], v1[8];
      if (full) {
        f4a x0 = *(const f4a*)(r0);
        f4a x1 = *(const f4a*)(r0 + 4);
        f4a y0 = *(const f4a*)(r1);
        f4a y1 = *(const f4a*)(r1 + 4);
        v0[0] = x0.x; v0[1] = x0.y; v0[2] = x0.z; v0[3] = x0.w;
        v0[4] = x1.x; v0[5] = x1.y; v0[6] = x1.z; v0[7] = x1.w;
        v1[0] = y0.x; v1[1] = y0.y; v1[2] = y0.z; v1[3] = y0.w;
        v1[4] = y1.x; v1[5] = y1.y; v1[6] = y1.z; v1[7] = y1.w;
      } else {
#pragma unroll
        for (int e = 0; e < 8; ++e) {
          int col = ncol0 + cg * 8 + e;
          v0[e] = (col < N) ? r0[e] : 0.f;
          v1[e] = (col < N) ? r1[e] : 0.f;
        }
      }
      int kk = kp * 2;
#pragma unroll
      for (int e = 0; e < 8; ++e) {
        int col = cg * 8 + e;
        unsigned int pk = (unsigned int)f2bf(v0[e]) | ((unsigned int)f2bf(v1[e]) << 16);
        *(unsigned int*)&Bt[col * 40 + kk] = pk;
      }
    }
    __syncthreads();  // drains vmcnt (global_load_lds) + lgkmcnt (ds_write)

    short8 af[4], bfr[4];
#pragma unroll
    for (int m = 0; m < 4; ++m) af[m] = *(const short8*)&As[a_off[m]];
#pragma unroll
    for (int n = 0; n < 4; ++n) bfr[n] = *(const short8*)&Bt[b_off[n]];
#pragma unroll
    for (int m = 0; m < 4; ++m)
#pragma unroll
      for (int n = 0; n < 4; ++n)
        acc[m][n] = __builtin_amdgcn_mfma_f32_16x16x32_bf16(af[m], bfr[n], acc[m][n], 0, 0, 0);
    __syncthreads();
  }

  // ---- epilogue: D frag col=lane&15, row=(lane>>4)*4+reg
#pragma unroll
  for (int n = 0; n < 4; ++n) {
    int col = ncol0 + bcol0 + n * 16 + (lane & 15);
    if (col < N) {
      float bv = bias ? bias[col] : 0.f;
#pragma unroll
      for (int m = 0; m < 4; ++m) {
        int row0 = mrow0 + brow0 + m * 16 + ((lane >> 4) << 2);
        f32x4 v = acc[m][n];
#pragma unroll
        for (int r = 0; r < 4; ++r)
          C[(size_t)(row0 + r) * N + col] = v[r] + bv;
      }
    }
  }
}

// ---------------- LSTM elementwise ----------------
__global__ __launch_bounds__(256) void k_lstm(
    const float* __restrict__ gates, const float* __restrict__ c,
    const float* __restrict__ bfp, const float* __restrict__ bigp,
    const float* __restrict__ bogp, const float* __restrict__ bip,
    float* __restrict__ hnew, float* __restrict__ cnew,
    unsigned short* __restrict__ hnew_bf) {
  int idx = blockIdx.x * 256 + threadIdx.x;   // < B*F
  int b = idx >> 11, j = idx & 2047;
  const float* g = gates + (size_t)b * 8192;
  float fp  = g[j]        + bfp[j];
  float igp = g[2048 + j] + bigp[j];
  float ogp = g[4096 + j] + bogp[j];
  float gp  = g[6144 + j] + bip[j];
  float f  = 1.f / (1.f + expf(-fp));
  float ig = 1.f / (1.f + expf(-igp));
  float og = 1.f / (1.f + expf(-ogp));
  float gt = tanhf(gp);
  float cn = f * c[idx] + ig * gt;
  float hn = og * tanhf(cn);
  cnew[idx] = cn;
  hnew[idx] = hn;
  hnew_bf[idx] = f2bf(hn);
}

extern "C" void kernel_launch(void* const* d_in, const int* in_sizes, int n_in,
                              void* d_out, int out_size, void* d_ws, size_t ws_size,
                              hipStream_t stream) {
  const int B = 2048, F = 2048, C = 50257;
  const int*   X    = (const int*)d_in[0];
  const float* h    = (const float*)d_in[1];
  const float* c    = (const float*)d_in[2];
  const float* emb  = (const float*)d_in[3];
  const float* Wf   = (const float*)d_in[4];
  const float* bf   = (const float*)d_in[5];
  const float* Wi   = (const float*)d_in[6];
  const float* bi   = (const float*)d_in[7];
  const float* Wig  = (const float*)d_in[8];
  const float* big  = (const float*)d_in[9];
  const float* Wog  = (const float*)d_in[10];
  const float* bog  = (const float*)d_in[11];
  const float* Wcls = (const float*)d_in[12];
  const float* bcls = (const float*)d_in[13];

  float* y    = (float*)d_out;                 // [B][C]
  float* hnew = y + (size_t)B * C;             // [B][F]
  float* cnew = hnew + (size_t)B * F;          // [B][F]

  char* ws = (char*)d_ws;
  unsigned short* xh    = (unsigned short*)ws;                          // B*4096 bf16 (16.8 MB)
  float*          gates = (float*)(ws + (size_t)B * 4096 * 2);          // B*8192 f32 (67.1 MB)
  unsigned short* hnbf  = (unsigned short*)(ws + (size_t)B * 4096 * 2 +
                                            (size_t)B * 8192 * 4);      // B*F bf16 (8.4 MB)

  // 1) xh = [emb[X], h] -> bf16
  k_build_xh<<<B, 256, 0, stream>>>(X, h, emb, xh);

  // 2) gates = xh @ [Wf | Wig | Wog | Wi]   (bias added in LSTM kernel)
  BParts bg{Wf, Wig, Wog, Wi};
  k_gemm<<<dim3(8192 / 128, B / 128), 256, 0, stream>>>(
      xh, bg, 2048, nullptr, gates, 8192, 4096, 4096);

  // 3) LSTM cell -> h_new, c_new (f32 to d_out) + h_new bf16 (ws)
  k_lstm<<<(B * F) / 256, 256, 0, stream>>>(gates, c, bf, big, bog, bi,
                                            hnew, cnew, hnbf);

  // 4) y = h_new @ Wcls + bcls
  BParts bc{Wcls, Wcls, Wcls, Wcls};
  k_gemm<<<dim3((C + 127) / 128, B / 128), 256, 0, stream>>>(
      hnbf, bc, C, bcls, y, C, 2048, 2048);
}

// Round 2
// 1134.496 us; speedup vs baseline: 1.6658x; 1.6658x over previous
//
#include <hip/hip_runtime.h>
#include <hip/hip_bf16.h>

typedef __attribute__((ext_vector_type(4))) float f32x4;
typedef __attribute__((ext_vector_type(8))) short short8;
typedef __attribute__((ext_vector_type(8))) unsigned short ushort8;
typedef __attribute__((ext_vector_type(4))) unsigned short u16x4;
typedef float f4a __attribute__((ext_vector_type(4), aligned(4)));  // 4B-aligned float4

__device__ __forceinline__ unsigned short f2bf(float f) {
  unsigned int u = __float_as_uint(f);
  u += 0x7fffu + ((u >> 16) & 1u);   // RNE (finite inputs only)
  return (unsigned short)(u >> 16);
}

// ---------------- build xh = [emb[X], h] as bf16 [2048][4096] ----------------
__global__ __launch_bounds__(256) void k_build_xh(
    const int* __restrict__ X, const float* __restrict__ h,
    const float* __restrict__ emb, unsigned short* __restrict__ xh) {
  int b = blockIdx.x;
  int tid = threadIdx.x;
  int j0 = tid * 16;   // 256 threads * 16 cols = 4096
  const float* src;
  if (j0 < 2048) {
    int xb = X[b];
    src = emb + (size_t)xb * 2048 + j0;
  } else {
    src = h + (size_t)b * 2048 + (j0 - 2048);
  }
  unsigned short* dst = xh + (size_t)b * 4096 + j0;
#pragma unroll
  for (int half = 0; half < 2; ++half) {
    float4 f0 = *(const float4*)(src + half * 8);
    float4 f1 = *(const float4*)(src + half * 8 + 4);
    ushort8 o;
    o[0] = f2bf(f0.x); o[1] = f2bf(f0.y); o[2] = f2bf(f0.z); o[3] = f2bf(f0.w);
    o[4] = f2bf(f1.x); o[5] = f2bf(f1.y); o[6] = f2bf(f1.z); o[7] = f2bf(f1.w);
    *(ushort8*)(dst + half * 8) = o;
  }
}

// ---------------- transpose + convert: W f32 [K][Nin] -> WT bf16 [Nin][K] ----------------
// reg-side 4x4 micro-transpose; per block 64k x 64n tile, 4 waves each own 16 k-rows.
__global__ __launch_bounds__(256) void k_cvt_t(
    const float* __restrict__ W, unsigned short* __restrict__ WT,
    int K, int Nin, int ldo, int rowoff) {
  int tid = threadIdx.x;
  int lane = tid & 63, w = tid >> 6;
  int n0 = blockIdx.x * 64, k0 = blockIdx.y * 64;
  int nb = n0 + 4 * (lane & 15);
  int kb = k0 + w * 16 + 4 * (lane >> 4);
  float v[4][4];
  if (nb + 3 < Nin) {
#pragma unroll
    for (int r = 0; r < 4; ++r) {
      f4a x = *(const f4a*)(W + (size_t)(kb + r) * Nin + nb);
      v[r][0] = x.x; v[r][1] = x.y; v[r][2] = x.z; v[r][3] = x.w;
    }
  } else {
#pragma unroll
    for (int r = 0; r < 4; ++r)
#pragma unroll
      for (int e = 0; e < 4; ++e)
        v[r][e] = (nb + e < Nin) ? W[(size_t)(kb + r) * Nin + nb + e] : 0.f;
  }
#pragma unroll
  for (int e = 0; e < 4; ++e) {
    if (nb + e < Nin) {
      u16x4 o;
      o[0] = f2bf(v[0][e]); o[1] = f2bf(v[1][e]);
      o[2] = f2bf(v[2][e]); o[3] = f2bf(v[3][e]);
      *(u16x4*)(WT + (size_t)(rowoff + nb + e) * ldo + kb) = o;
    }
  }
}

// ---------------- bf16 GEMM (m97 structure): C[M][N] = A[M][K] @ Bt[N][K]^T ----------------
// 128x128 tile, BK=32, 4 waves of 64x64, both operands via global_load_lds w=16.
__global__ __launch_bounds__(256) void k_gemm(
    const unsigned short* __restrict__ A,   // [M][lda] bf16
    const unsigned short* __restrict__ Bt,  // [>=N][K] bf16 (B columns as rows)
    const float* __restrict__ bias, float* __restrict__ C,
    int N, int K, int lda) {
  __shared__ unsigned short As[128 * 32];
  __shared__ unsigned short Bs[128 * 32];

  const int tid = threadIdx.x;
  const int lane = tid & 63;
  const int wid = tid >> 6;

  // XCD-aware bijective swizzle (nwg % 8 == 0 in all our launches); M-tiles fastest.
  int nwg = gridDim.x * gridDim.y;
  int o = blockIdx.y * gridDim.x + blockIdx.x;
  int q = nwg >> 3;
  int s = (o & 7) * q + (o >> 3);
  const int mrow0 = (s % gridDim.x) * 128;
  const int ncol0 = (s / gridDim.x) * 128;

  f32x4 acc[4][4];
#pragma unroll
  for (int m = 0; m < 4; ++m)
#pragma unroll
    for (int n = 0; n < 4; ++n) acc[m][n] = {0.f, 0.f, 0.f, 0.f};

  const int wr = wid >> 1, wc = wid & 1;
  const int brow0 = wr * 64, bcol0 = wc * 64;

  int a_off[4], b_off[4];
#pragma unroll
  for (int m = 0; m < 4; ++m)
    a_off[m] = (brow0 + m * 16 + (lane & 15)) * 32 + ((lane >> 4) << 3);
#pragma unroll
  for (int n = 0; n < 4; ++n)
    b_off[n] = (bcol0 + n * 16 + (lane & 15)) * 32 + ((lane >> 4) << 3);

  for (int k0 = 0; k0 < K; k0 += 32) {
#pragma unroll
    for (int i = 0; i < 2; ++i) {
      int slot = i * 256 + tid;          // 0..511 ; 16B per slot
      int r = slot >> 2, ck = slot & 3;
      unsigned short* la = As + (size_t)(i * 256 + wid * 64) * 8;  // wave-uniform base
      unsigned short* lb = Bs + (size_t)(i * 256 + wid * 64) * 8;
      const unsigned short* ga = A + (size_t)(mrow0 + r) * lda + k0 + ck * 8;
      const unsigned short* gb = Bt + (size_t)(ncol0 + r) * K + k0 + ck * 8;
      __builtin_amdgcn_global_load_lds(
          (const __attribute__((address_space(1))) void*)ga,
          (__attribute__((address_space(3))) void*)la, 16, 0, 0);
      __builtin_amdgcn_global_load_lds(
          (const __attribute__((address_space(1))) void*)gb,
          (__attribute__((address_space(3))) void*)lb, 16, 0, 0);
    }
    __syncthreads();

    short8 af[4], bfr[4];
#pragma unroll
    for (int m = 0; m < 4; ++m) af[m] = *(const short8*)&As[a_off[m]];
#pragma unroll
    for (int n = 0; n < 4; ++n) bfr[n] = *(const short8*)&Bs[b_off[n]];
#pragma unroll
    for (int m = 0; m < 4; ++m)
#pragma unroll
      for (int n = 0; n < 4; ++n)
        acc[m][n] = __builtin_amdgcn_mfma_f32_16x16x32_bf16(af[m], bfr[n], acc[m][n], 0, 0, 0);
    __syncthreads();
  }

  // epilogue: D frag col=lane&15, row=(lane>>4)*4+reg
#pragma unroll
  for (int n = 0; n < 4; ++n) {
    int col = ncol0 + bcol0 + n * 16 + (lane & 15);
    if (col < N) {
      float bv = bias ? bias[col] : 0.f;
#pragma unroll
      for (int m = 0; m < 4; ++m) {
        int row0 = mrow0 + brow0 + m * 16 + ((lane >> 4) << 2);
        f32x4 v = acc[m][n];
#pragma unroll
        for (int r = 0; r < 4; ++r)
          C[(size_t)(row0 + r) * N + col] = v[r] + bv;
      }
    }
  }
}

// ---------------- LSTM elementwise ----------------
__global__ __launch_bounds__(256) void k_lstm(
    const float* __restrict__ gates, const float* __restrict__ c,
    const float* __restrict__ bfp, const float* __restrict__ bigp,
    const float* __restrict__ bogp, const float* __restrict__ bip,
    float* __restrict__ hnew, float* __restrict__ cnew,
    unsigned short* __restrict__ hnew_bf) {
  int idx = blockIdx.x * 256 + threadIdx.x;   // < B*F
  int b = idx >> 11, j = idx & 2047;
  const float* g = gates + (size_t)b * 8192;
  float fp  = g[j]        + bfp[j];
  float igp = g[2048 + j] + bigp[j];
  float ogp = g[4096 + j] + bogp[j];
  float gp  = g[6144 + j] + bip[j];
  float f  = 1.f / (1.f + expf(-fp));
  float ig = 1.f / (1.f + expf(-igp));
  float og = 1.f / (1.f + expf(-ogp));
  float gt = tanhf(gp);
  float cn = f * c[idx] + ig * gt;
  float hn = og * tanhf(cn);
  cnew[idx] = cn;
  hnew[idx] = hn;
  hnew_bf[idx] = f2bf(hn);
}

extern "C" void kernel_launch(void* const* d_in, const int* in_sizes, int n_in,
                              void* d_out, int out_size, void* d_ws, size_t ws_size,
                              hipStream_t stream) {
  const int B = 2048, F = 2048, C = 50257;
  const int NT = 50304;                       // C rounded up to 128
  const int*   X    = (const int*)d_in[0];
  const float* h    = (const float*)d_in[1];
  const float* c    = (const float*)d_in[2];
  const float* emb  = (const float*)d_in[3];
  const float* Wf   = (const float*)d_in[4];
  const float* bf   = (const float*)d_in[5];
  const float* Wi   = (const float*)d_in[6];
  const float* bi   = (const float*)d_in[7];
  const float* Wig  = (const float*)d_in[8];
  const float* big  = (const float*)d_in[9];
  const float* Wog  = (const float*)d_in[10];
  const float* bog  = (const float*)d_in[11];
  const float* Wcls = (const float*)d_in[12];
  const float* bcls = (const float*)d_in[13];

  float* y    = (float*)d_out;                 // [B][C]
  float* hnew = y + (size_t)B * C;             // [B][F]
  float* cnew = hnew + (size_t)B * F;          // [B][F]

  // ws layout (WclsT aliases xh/WgT/gates, which are dead by the time it's written):
  //   [0, 8.4MB)      hnbf   (B*F bf16)
  //   [8.4, 25.2)     xh     (B*4096 bf16)      \
  //   [25.2, 92.3)    WgT    (8192*4096 bf16)    } aliased by WclsT [8.4, 214.4)
  //   [92.3, 159.4)   gates  (B*8192 f32)       /
  char* ws = (char*)d_ws;
  unsigned short* hnbf  = (unsigned short*)ws;
  unsigned short* xh    = (unsigned short*)(ws + 8388608);
  unsigned short* WgT   = (unsigned short*)(ws + 25165824);
  float*          gates = (float*)(ws + 92274688);
  unsigned short* WclsT = (unsigned short*)(ws + 8388608);   // [NT][2048] bf16

  // 1) xh = [emb[X], h] -> bf16
  k_build_xh<<<B, 256, 0, stream>>>(X, h, emb, xh);

  // 2) WgT = concat(Wf,Wig,Wog,Wi, axis=1)^T as bf16 [8192][4096]
  const float* parts[4] = {Wf, Wig, Wog, Wi};
  for (int p = 0; p < 4; ++p)
    k_cvt_t<<<dim3(32, 64), 256, 0, stream>>>(parts[p], WgT, 4096, 2048, 4096, p * 2048);

  // 3) gates = xh @ Wg   (bias folded into LSTM kernel)
  k_gemm<<<dim3(16, 64), 256, 0, stream>>>(xh, WgT, nullptr, gates, 8192, 4096, 4096);

  // 4) LSTM cell -> h_new, c_new (f32 to d_out) + h_new bf16 (ws)
  k_lstm<<<(B * F) / 256, 256, 0, stream>>>(gates, c, bf, big, bog, bi,
                                            hnew, cnew, hnbf);

  // 5) WclsT = Wcls^T bf16 [50304][2048] (pad rows never written; unused results masked)
  k_cvt_t<<<dim3(786, 32), 256, 0, stream>>>(Wcls, WclsT, 2048, C, 2048, 0);

  // 6) y = h_new @ Wcls + bcls
  k_gemm<<<dim3(16, NT / 128), 256, 0, stream>>>(hnbf, WclsT, bcls, y, C, 2048, 2048);
}

// Round 3
// 790.141 us; speedup vs baseline: 2.3918x; 1.4358x over previous
//
#include <hip/hip_runtime.h>
#include <hip/hip_bf16.h>

typedef __attribute__((ext_vector_type(4))) float f32x4;
typedef __attribute__((ext_vector_type(8))) short short8;
typedef __attribute__((ext_vector_type(8))) unsigned short ushort8;
typedef __attribute__((ext_vector_type(4))) unsigned short u16x4;
typedef float f4a __attribute__((ext_vector_type(4), aligned(4)));

__device__ __forceinline__ unsigned short f2bf(float f) {
  unsigned int u = __float_as_uint(f);
  u += 0x7fffu + ((u >> 16) & 1u);   // RNE (finite inputs only)
  return (unsigned short)(u >> 16);
}

#define BARRIER do { asm volatile("" ::: "memory"); __builtin_amdgcn_s_barrier(); asm volatile("" ::: "memory"); } while(0)
#define LGKM0   do { asm volatile("s_waitcnt lgkmcnt(0)" ::: "memory"); __builtin_amdgcn_sched_barrier(0); } while(0)
#define VMW(n)  asm volatile("s_waitcnt vmcnt(" #n ")" ::: "memory")

// ---------------- build xh = [emb[X], h] as bf16 [2048][4096] ----------------
__global__ __launch_bounds__(256) void k_build_xh(
    const int* __restrict__ X, const float* __restrict__ h,
    const float* __restrict__ emb, unsigned short* __restrict__ xh) {
  int b = blockIdx.x;
  int tid = threadIdx.x;
  int j0 = tid * 16;
  const float* src;
  if (j0 < 2048) {
    int xb = X[b];
    src = emb + (size_t)xb * 2048 + j0;
  } else {
    src = h + (size_t)b * 2048 + (j0 - 2048);
  }
  unsigned short* dst = xh + (size_t)b * 4096 + j0;
#pragma unroll
  for (int half = 0; half < 2; ++half) {
    float4 f0 = *(const float4*)(src + half * 8);
    float4 f1 = *(const float4*)(src + half * 8 + 4);
    ushort8 o;
    o[0] = f2bf(f0.x); o[1] = f2bf(f0.y); o[2] = f2bf(f0.z); o[3] = f2bf(f0.w);
    o[4] = f2bf(f1.x); o[5] = f2bf(f1.y); o[6] = f2bf(f1.z); o[7] = f2bf(f1.w);
    *(ushort8*)(dst + half * 8) = o;
  }
}

// ---------------- transpose + convert: W f32 [K][Nin] -> WT bf16 [Nin][K] ----------------
__global__ __launch_bounds__(256) void k_cvt_t(
    const float* __restrict__ W, unsigned short* __restrict__ WT,
    int K, int Nin, int ldo, int rowoff) {
  int tid = threadIdx.x;
  int lane = tid & 63, w = tid >> 6;
  int n0 = blockIdx.x * 64, k0 = blockIdx.y * 64;
  int nb = n0 + 4 * (lane & 15);
  int kb = k0 + w * 16 + 4 * (lane >> 4);
  float v[4][4];
  if (nb + 3 < Nin) {
#pragma unroll
    for (int r = 0; r < 4; ++r) {
      f4a x = *(const f4a*)(W + (size_t)(kb + r) * Nin + nb);
      v[r][0] = x.x; v[r][1] = x.y; v[r][2] = x.z; v[r][3] = x.w;
    }
  } else {
#pragma unroll
    for (int r = 0; r < 4; ++r)
#pragma unroll
      for (int e = 0; e < 4; ++e)
        v[r][e] = (nb + e < Nin) ? W[(size_t)(kb + r) * Nin + nb + e] : 0.f;
  }
#pragma unroll
  for (int e = 0; e < 4; ++e) {
    if (nb + e < Nin) {
      u16x4 o;
      o[0] = f2bf(v[0][e]); o[1] = f2bf(v[1][e]);
      o[2] = f2bf(v[2][e]); o[3] = f2bf(v[3][e]);
      *(u16x4*)(WT + (size_t)(rowoff + nb + e) * ldo + kb) = o;
    }
  }
}

// ---------------- 256x256 8-phase bf16 GEMM (T2+T3+T4+T5) ----------------
// C[M=2048][N] = A[M][K] @ Bt[N][K]^T ; BK=64, 512 thr = 8 waves (2M x 4N),
// per-wave 128x64 out. LDS 128KB: units A(buf,half)=16KB @ (buf*2+h)*16K,
// B units @ 64K + (buf*2+h)*16K. Swizzle: phys = logical ^ ((row&7)<<4).
__device__ __forceinline__ void stage_unit(
    const unsigned short* __restrict__ gp0, int ld, int row0, int rowmax,
    int ktile, unsigned char* smem, unsigned lds_off, int tid, int wid) {
#pragma unroll
  for (int i = 0; i < 2; ++i) {
    unsigned phys = (unsigned)(i * 512 + tid) * 16u;
    unsigned logi = phys ^ (((phys >> 7) & 7u) << 4);
    int r = (int)(logi >> 7);
    int kb = (int)(logi & 127u);
    int grow = row0 + r;
    grow = (grow > rowmax) ? rowmax : grow;
    const unsigned short* gp = gp0 + (size_t)grow * ld + ktile * 64 + (kb >> 1);
    __builtin_amdgcn_global_load_lds(
        (const __attribute__((address_space(1))) void*)gp,
        (__attribute__((address_space(3))) void*)(smem + lds_off + (unsigned)(i * 512 + wid * 64) * 16u),
        16, 0, 0);
  }
}

__device__ __forceinline__ short8 ld_fragA(const unsigned char* smem, int buf, int half,
                                           int row_local, int ks, int lane) {
  unsigned kbyte = (unsigned)(ks * 64 + ((lane >> 4) << 4));
  unsigned off = (unsigned)(buf * 2 + half) * 16384u + (unsigned)row_local * 128u
               + (kbyte ^ (((unsigned)row_local & 7u) << 4));
  return *(const short8*)(smem + off);
}
__device__ __forceinline__ short8 ld_fragB(const unsigned char* smem, int buf, int half,
                                           int col_local, int ks, int lane) {
  unsigned kbyte = (unsigned)(ks * 64 + ((lane >> 4) << 4));
  unsigned off = 65536u + (unsigned)(buf * 2 + half) * 16384u + (unsigned)col_local * 128u
               + (kbyte ^ (((unsigned)col_local & 7u) << 4));
  return *(const short8*)(smem + off);
}

__global__ __launch_bounds__(512, 1) void k_gemm256(
    const unsigned short* __restrict__ A, const unsigned short* __restrict__ Bt,
    const float* __restrict__ bias, float* __restrict__ C,
    int N, int K, int lda, int ldb, int rowmaxB) {
  __shared__ __align__(16) unsigned char smem[131072];
  const int tid = threadIdx.x, lane = tid & 63, wid = tid >> 6;
  const int wr = wid >> 2, wc = wid & 3;

  // XCD-aware bijective swizzle; M-tiles (8) vary fastest within an XCD chunk.
  int nwg = gridDim.x * gridDim.y;          // gridDim.x == 8 (M-tiles)
  int o = blockIdx.y * gridDim.x + blockIdx.x;
  int q = nwg >> 3;
  int s = (o & 7) * q + (o >> 3);
  const int mrow0 = (s & 7) * 256;
  const int ncol0 = (s >> 3) * 256;

  const int NKT = K >> 6;

  f32x4 acc[8][4];
#pragma unroll
  for (int m = 0; m < 8; ++m)
#pragma unroll
    for (int n = 0; n < 4; ++n) acc[m][n] = {0.f, 0.f, 0.f, 0.f};

  short8 a_frag[4][2], b_frag[2][2][2];

#define ST_A(buf, h, t) stage_unit(A, lda, mrow0 + (h) * 128, 0x7fffffff, (t), smem, (unsigned)((buf) * 2 + (h)) * 16384u, tid, wid)
#define ST_B(buf, h, t) stage_unit(Bt, ldb, ncol0 + (h) * 128, rowmaxB, (t), smem, 65536u + (unsigned)((buf) * 2 + (h)) * 16384u, tid, wid)
#define RD_A(buf, mh) do { _Pragma("unroll") for (int mm = 0; mm < 4; ++mm) { int rl = (mh) * 64 + mm * 16 + (lane & 15); _Pragma("unroll") for (int ks = 0; ks < 2; ++ks) a_frag[mm][ks] = ld_fragA(smem, (buf), wr, rl, ks, lane); } } while (0)
#define RD_B(buf, nh) do { _Pragma("unroll") for (int nn = 0; nn < 2; ++nn) { int cl = (wc & 1) * 64 + (nh) * 32 + nn * 16 + (lane & 15); _Pragma("unroll") for (int ks = 0; ks < 2; ++ks) b_frag[nh][nn][ks] = ld_fragB(smem, (buf), (wc >> 1), cl, ks, lane); } } while (0)
#define MF(mh, nh) do { __builtin_amdgcn_s_setprio(1); _Pragma("unroll") for (int mm = 0; mm < 4; ++mm) _Pragma("unroll") for (int nn = 0; nn < 2; ++nn) _Pragma("unroll") for (int ks = 0; ks < 2; ++ks) acc[(mh) * 4 + mm][(nh) * 2 + nn] = __builtin_amdgcn_mfma_f32_16x16x32_bf16(a_frag[mm][ks], b_frag[(nh)][nn][ks], acc[(mh) * 4 + mm][(nh) * 2 + nn], 0, 0, 0); __builtin_amdgcn_s_setprio(0); } while (0)

  // Prologue: t0 fully + t1's B halves. 12 loads/thread; retire t0 (8), keep B(t1) in flight.
  ST_A(0, 0, 0); ST_A(0, 1, 0); ST_B(0, 0, 0); ST_B(0, 1, 0);
  ST_B(1, 0, 1); ST_B(1, 1, 1);
  VMW(4); BARRIER;

  // Main: iterations consume (t0,t0+1); stages reference t0+1..t0+3 (all valid).
  for (int t0 = 0; t0 + 3 < NKT; t0 += 2) {
    RD_A(0, 0); RD_B(0, 0); ST_A(1, 0, t0 + 1);
    BARRIER; LGKM0; MF(0, 0); BARRIER;                 // ph1
    RD_B(0, 1); ST_A(1, 1, t0 + 1);
    BARRIER; LGKM0; MF(0, 1); BARRIER;                 // ph2
    RD_A(0, 1); ST_B(0, 0, t0 + 2);
    BARRIER; LGKM0; MF(1, 1); BARRIER;                 // ph3
    ST_B(0, 1, t0 + 2); VMW(4);
    BARRIER; LGKM0; MF(1, 0); BARRIER;                 // ph4 (t1 landed)
    RD_A(1, 0); RD_B(1, 0); ST_A(0, 0, t0 + 2);
    BARRIER; LGKM0; MF(0, 0); BARRIER;                 // ph5
    RD_B(1, 1); ST_A(0, 1, t0 + 2);
    BARRIER; LGKM0; MF(0, 1); BARRIER;                 // ph6
    RD_A(1, 1); ST_B(1, 0, t0 + 3);
    BARRIER; LGKM0; MF(1, 1); BARRIER;                 // ph7
    ST_B(1, 1, t0 + 3); VMW(4);
    BARRIER; LGKM0; MF(1, 0); BARRIER;                 // ph8 (t2 landed)
  }

  // Peeled final pair (t0 = NKT-2, t1 = NKT-1): no t+2/t+3 stages.
  {
    const int t1 = NKT - 1;
    RD_A(0, 0); RD_B(0, 0); ST_A(1, 0, t1);
    BARRIER; LGKM0; MF(0, 0); BARRIER;
    RD_B(0, 1); ST_A(1, 1, t1);
    BARRIER; LGKM0; MF(0, 1); BARRIER;
    RD_A(0, 1);
    BARRIER; LGKM0; MF(1, 1); BARRIER;
    VMW(0);
    BARRIER; LGKM0; MF(1, 0); BARRIER;
    RD_A(1, 0); RD_B(1, 0);
    BARRIER; LGKM0; MF(0, 0); BARRIER;
    RD_B(1, 1);
    BARRIER; LGKM0; MF(0, 1); BARRIER;
    RD_A(1, 1);
    BARRIER; LGKM0; MF(1, 1); BARRIER;
    BARRIER; LGKM0; MF(1, 0); BARRIER;
  }

  // Epilogue: per-wave LDS round-trip -> 256B-contiguous row stores (full-line writes).
  // Wave region: 16KB at smem + wid*16384, viewed as float[64][64], cols rotated by
  // ((row>>2)&3)*16 to kill write bank conflicts.
  {
    float* wlds = (float*)(smem + (unsigned)wid * 16384u);
    const int gcol = ncol0 + wc * 64 + lane;
    const bool cok = (gcol < N);
    const float bv = (bias != nullptr && cok) ? bias[gcol] : 0.f;
#pragma unroll
    for (int mh = 0; mh < 2; ++mh) {
#pragma unroll
      for (int mm = 0; mm < 4; ++mm)
#pragma unroll
        for (int nn = 0; nn < 4; ++nn) {
#pragma unroll
          for (int r = 0; r < 4; ++r) {
            int row = mm * 16 + ((lane >> 4) << 2) + r;
            int colv = nn * 16 + (lane & 15);
            int cs = (colv + ((row >> 2) & 3) * 16) & 63;
            wlds[row * 64 + cs] = acc[mh * 4 + mm][nn][r];
          }
        }
#pragma unroll 8
      for (int row = 0; row < 64; ++row) {
        int cs = (lane + ((row >> 2) & 3) * 16) & 63;
        float v = wlds[row * 64 + cs] + bv;
        int grow = mrow0 + wr * 128 + mh * 64 + row;
        if (cok) C[(size_t)grow * N + gcol] = v;
      }
    }
  }
#undef ST_A
#undef ST_B
#undef RD_A
#undef RD_B
#undef MF
}

// ---------------- LSTM elementwise ----------------
__global__ __launch_bounds__(256) void k_lstm(
    const float* __restrict__ gates, const float* __restrict__ c,
    const float* __restrict__ bfp, const float* __restrict__ bigp,
    const float* __restrict__ bogp, const float* __restrict__ bip,
    float* __restrict__ hnew, float* __restrict__ cnew,
    unsigned short* __restrict__ hnew_bf) {
  int idx = blockIdx.x * 256 + threadIdx.x;
  int b = idx >> 11, j = idx & 2047;
  const float* g = gates + (size_t)b * 8192;
  float fp  = g[j]        + bfp[j];
  float igp = g[2048 + j] + bigp[j];
  float ogp = g[4096 + j] + bogp[j];
  float gp  = g[6144 + j] + bip[j];
  float f  = 1.f / (1.f + expf(-fp));
  float ig = 1.f / (1.f + expf(-igp));
  float og = 1.f / (1.f + expf(-ogp));
  float gt = tanhf(gp);
  float cn = f * c[idx] + ig * gt;
  float hn = og * tanhf(cn);
  cnew[idx] = cn;
  hnew[idx] = hn;
  hnew_bf[idx] = f2bf(hn);
}

extern "C" void kernel_launch(void* const* d_in, const int* in_sizes, int n_in,
                              void* d_out, int out_size, void* d_ws, size_t ws_size,
                              hipStream_t stream) {
  const int B = 2048, F = 2048, C = 50257;
  const int NT = 50304;                       // Bt rows allocated (C rounded to 128)
  const int*   X    = (const int*)d_in[0];
  const float* h    = (const float*)d_in[1];
  const float* c    = (const float*)d_in[2];
  const float* emb  = (const float*)d_in[3];
  const float* Wf   = (const float*)d_in[4];
  const float* bf   = (const float*)d_in[5];
  const float* Wi   = (const float*)d_in[6];
  const float* bi   = (const float*)d_in[7];
  const float* Wig  = (const float*)d_in[8];
  const float* big  = (const float*)d_in[9];
  const float* Wog  = (const float*)d_in[10];
  const float* bog  = (const float*)d_in[11];
  const float* Wcls = (const float*)d_in[12];
  const float* bcls = (const float*)d_in[13];

  float* y    = (float*)d_out;                 // [B][C]
  float* hnew = y + (size_t)B * C;             // [B][F]
  float* cnew = hnew + (size_t)B * F;          // [B][F]

  // ws layout (WclsT aliases xh/WgT/gates, dead by the time it's written):
  char* ws = (char*)d_ws;
  unsigned short* hnbf  = (unsigned short*)ws;                 // [0, 8.4MB)
  unsigned short* xh    = (unsigned short*)(ws + 8388608);     // [8.4, 25.2)
  unsigned short* WgT   = (unsigned short*)(ws + 25165824);    // [25.2, 92.3)
  float*          gates = (float*)(ws + 92274688);             // [92.3, 159.4)
  unsigned short* WclsT = (unsigned short*)(ws + 8388608);     // [8.4, 214.4) [NT][2048]

  // 1) xh = [emb[X], h] -> bf16
  k_build_xh<<<B, 256, 0, stream>>>(X, h, emb, xh);

  // 2) WgT = concat(Wf,Wig,Wog,Wi, axis=1)^T as bf16 [8192][4096]
  const float* parts[4] = {Wf, Wig, Wog, Wi};
  for (int p = 0; p < 4; ++p)
    k_cvt_t<<<dim3(32, 64), 256, 0, stream>>>(parts[p], WgT, 4096, 2048, 4096, p * 2048);

  // 3) gates = xh @ Wg   (bias folded into LSTM kernel)
  k_gemm256<<<dim3(8, 32), 512, 0, stream>>>(xh, WgT, nullptr, gates, 8192, 4096, 4096, 4096, 8191);

  // 4) LSTM cell -> h_new, c_new (f32 to d_out) + h_new bf16 (ws)
  k_lstm<<<(B * F) / 256, 256, 0, stream>>>(gates, c, bf, big, bog, bi,
                                            hnew, cnew, hnbf);

  // 5) WclsT = Wcls^T bf16 [NT][2048]
  k_cvt_t<<<dim3(786, 32), 256, 0, stream>>>(Wcls, WclsT, 2048, C, 2048, 0);

  // 6) y = h_new @ Wcls + bcls  (197 N-tiles of 256; B-stage rows clamped to NT-1)
  k_gemm256<<<dim3(8, 197), 512, 0, stream>>>(hnbf, WclsT, bcls, y, C, 2048, 2048, 2048, NT - 1);
}

// Round 5
// 783.644 us; speedup vs baseline: 2.4116x; 1.0083x over previous
//
#include <hip/hip_runtime.h>
#include <hip/hip_bf16.h>

typedef __attribute__((ext_vector_type(4))) float f32x4;
typedef __attribute__((ext_vector_type(8))) short short8;
typedef __attribute__((ext_vector_type(8))) unsigned short ushort8;
typedef __attribute__((ext_vector_type(4))) unsigned short u16x4;
typedef float f4a __attribute__((ext_vector_type(4), aligned(4)));

__device__ __forceinline__ unsigned short f2bf(float f) {
  unsigned int u = __float_as_uint(f);
  u += 0x7fffu + ((u >> 16) & 1u);   // RNE (finite inputs only)
  return (unsigned short)(u >> 16);
}

#define BARRIER do { asm volatile("" ::: "memory"); __builtin_amdgcn_s_barrier(); asm volatile("" ::: "memory"); } while(0)
#define LGKM    asm volatile("s_waitcnt lgkmcnt(0)" ::: "memory")
#define VMW(n)  asm volatile("s_waitcnt vmcnt(" #n ")" ::: "memory")

// ---------------- build xh = [emb[X], h] as bf16 [2048][4096] ----------------
__global__ __launch_bounds__(256) void k_build_xh(
    const int* __restrict__ X, const float* __restrict__ h,
    const float* __restrict__ emb, unsigned short* __restrict__ xh) {
  int b = blockIdx.x;
  int tid = threadIdx.x;
  int j0 = tid * 16;
  const float* src;
  if (j0 < 2048) {
    int xb = X[b];
    src = emb + (size_t)xb * 2048 + j0;
  } else {
    src = h + (size_t)b * 2048 + (j0 - 2048);
  }
  unsigned short* dst = xh + (size_t)b * 4096 + j0;
#pragma unroll
  for (int half = 0; half < 2; ++half) {
    float4 f0 = *(const float4*)(src + half * 8);
    float4 f1 = *(const float4*)(src + half * 8 + 4);
    ushort8 o;
    o[0] = f2bf(f0.x); o[1] = f2bf(f0.y); o[2] = f2bf(f0.z); o[3] = f2bf(f0.w);
    o[4] = f2bf(f1.x); o[5] = f2bf(f1.y); o[6] = f2bf(f1.z); o[7] = f2bf(f1.w);
    *(ushort8*)(dst + half * 8) = o;
  }
}

// ---------------- WgT: 4 gate weights -> bf16, transposed, gate-interleaved ----------------
// out row for (gate g, col j) = (j>>6)*256 + g*64 + (j&63); ld 4096.
__global__ __launch_bounds__(256) void k_cvt_wg(
    const float* __restrict__ W0, const float* __restrict__ W1,
    const float* __restrict__ W2, const float* __restrict__ W3,
    unsigned short* __restrict__ WT) {
  const int g = blockIdx.z;
  const float* W = (g == 0) ? W0 : (g == 1) ? W1 : (g == 2) ? W2 : W3;
  int tid = threadIdx.x, lane = tid & 63, w = tid >> 6;
  int n0 = blockIdx.x * 64, k0 = blockIdx.y * 64;
  int nb = n0 + 4 * (lane & 15);
  int kb = k0 + w * 16 + 4 * (lane >> 4);
  float v[4][4];
#pragma unroll
  for (int r = 0; r < 4; ++r) {
    f4a x = *(const f4a*)(W + (size_t)(kb + r) * 2048 + nb);
    v[r][0] = x.x; v[r][1] = x.y; v[r][2] = x.z; v[r][3] = x.w;
  }
#pragma unroll
  for (int e = 0; e < 4; ++e) {
    int col = nb + e;
    int row = ((col >> 6) << 8) + g * 64 + (col & 63);
    u16x4 o;
    o[0] = f2bf(v[0][e]); o[1] = f2bf(v[1][e]);
    o[2] = f2bf(v[2][e]); o[3] = f2bf(v[3][e]);
    *(u16x4*)(WT + (size_t)row * 4096 + kb) = o;
  }
}

// ---------------- transpose + convert: W f32 [K][Nin] -> WT bf16 [Nin][K] ----------------
__global__ __launch_bounds__(256) void k_cvt_t(
    const float* __restrict__ W, unsigned short* __restrict__ WT,
    int K, int Nin, int ldo) {
  int tid = threadIdx.x;
  int lane = tid & 63, w = tid >> 6;
  int n0 = blockIdx.x * 64, k0 = blockIdx.y * 64;
  int nb = n0 + 4 * (lane & 15);
  int kb = k0 + w * 16 + 4 * (lane >> 4);
  float v[4][4];
  if (nb + 3 < Nin) {
#pragma unroll
    for (int r = 0; r < 4; ++r) {
      f4a x = *(const f4a*)(W + (size_t)(kb + r) * Nin + nb);
      v[r][0] = x.x; v[r][1] = x.y; v[r][2] = x.z; v[r][3] = x.w;
    }
  } else {
#pragma unroll
    for (int r = 0; r < 4; ++r)
#pragma unroll
      for (int e = 0; e < 4; ++e)
        v[r][e] = (nb + e < Nin) ? W[(size_t)(kb + r) * Nin + nb + e] : 0.f;
  }
#pragma unroll
  for (int e = 0; e < 4; ++e) {
    if (nb + e < Nin) {
      u16x4 o;
      o[0] = f2bf(v[0][e]); o[1] = f2bf(v[1][e]);
      o[2] = f2bf(v[2][e]); o[3] = f2bf(v[3][e]);
      *(u16x4*)(WT + (size_t)(nb + e) * ldo + kb) = o;
    }
  }
}

// ---------------- 256x256 8-phase bf16 GEMM (T2+T3+T4+T5) ----------------
struct EpiP {
  const float *c, *b0, *b1, *b2, *b3;   // c, bias(f), bias(ig), bias(og), bias(g)
  float *hnew, *cnew;
  unsigned short* hnbf;
};

__device__ __forceinline__ short8 ld_fragA(const unsigned char* smem, int buf, int half,
                                           int row_local, int ks, int lane) {
  unsigned kbyte = (unsigned)(ks * 64 + ((lane >> 4) << 4));
  unsigned off = (unsigned)(buf * 2 + half) * 16384u + (unsigned)row_local * 128u
               + (kbyte ^ (((unsigned)row_local & 7u) << 4));
  return *(const short8*)(smem + off);
}
__device__ __forceinline__ short8 ld_fragB(const unsigned char* smem, int buf, int half,
                                           int col_local, int ks, int lane) {
  unsigned kbyte = (unsigned)(ks * 64 + ((lane >> 4) << 4));
  unsigned off = 65536u + (unsigned)(buf * 2 + half) * 16384u + (unsigned)col_local * 128u
               + (kbyte ^ (((unsigned)col_local & 7u) << 4));
  return *(const short8*)(smem + off);
}

template <int EPI>
__global__ __launch_bounds__(512, 1) void k_gemm256(
    const unsigned short* __restrict__ A, const unsigned short* __restrict__ Bt,
    const float* __restrict__ bias, float* __restrict__ C,
    int N, int K, int lda, int ldb, int rowmaxB, EpiP P) {
  __shared__ __align__(16) unsigned char smem[131072];
  const int tid = threadIdx.x, lane = tid & 63, wid = tid >> 6;
  const int wr = wid >> 2, wc = wid & 3;

  // XCD-aware bijective swizzle; gridDim.x == 8 (M-tiles vary fastest).
  int nwg = gridDim.x * gridDim.y;
  int o = blockIdx.y * gridDim.x + blockIdx.x;
  int q = nwg >> 3;
  int s = (o & 7) * q + (o >> 3);
  const int mrow0 = (s & 7) * 256;
  const int ncol0 = (s >> 3) * 256;

  const int NKT = K >> 6;

  // ---- hoisted per-thread stage offsets (elements) ----
  unsigned vA[2], vB[2][2];
#pragma unroll
  for (int i = 0; i < 2; ++i) {
    unsigned phys = (unsigned)(i * 512 + tid) * 16u;
    unsigned logi = phys ^ (((phys >> 7) & 7u) << 4);
    unsigned r = logi >> 7;
    unsigned kbe = (logi & 127u) >> 1;
    vA[i] = r * (unsigned)lda + kbe;
#pragma unroll
    for (int hh = 0; hh < 2; ++hh) {
      int br = ncol0 + hh * 128 + (int)r;
      br = (br > rowmaxB) ? rowmaxB : br;
      vB[hh][i] = (unsigned)br * (unsigned)ldb + kbe;
    }
  }
  const unsigned short* Ab0 = A + (size_t)mrow0 * lda;
  const unsigned short* Ab1 = Ab0 + (size_t)128 * lda;

  f32x4 acc[8][4];
#pragma unroll
  for (int m = 0; m < 8; ++m)
#pragma unroll
    for (int n = 0; n < 4; ++n) acc[m][n] = {0.f, 0.f, 0.f, 0.f};

  short8 a_frag[4][2], b_frag[2][2][2];

#define STG(baseptr, v, ldsoff) __builtin_amdgcn_global_load_lds( \
    (const __attribute__((address_space(1))) void*)((baseptr) + (v)), \
    (__attribute__((address_space(3))) void*)(smem + (ldsoff)), 16, 0, 0)
#define ST_A(buf, hh, t) do { const unsigned short* _b = (hh ? Ab1 : Ab0) + (size_t)(t) * 64; \
    STG(_b, vA[0], (unsigned)((buf) * 2 + (hh)) * 16384u + (unsigned)(wid * 1024)); \
    STG(_b, vA[1], (unsigned)((buf) * 2 + (hh)) * 16384u + (unsigned)(8192 + wid * 1024)); } while (0)
#define ST_B(buf, hh, t) do { const unsigned short* _b = Bt + (size_t)(t) * 64; \
    STG(_b, vB[hh][0], 65536u + (unsigned)((buf) * 2 + (hh)) * 16384u + (unsigned)(wid * 1024)); \
    STG(_b, vB[hh][1], 65536u + (unsigned)((buf) * 2 + (hh)) * 16384u + (unsigned)(8192 + wid * 1024)); } while (0)
#define RD_A(buf, mh) do { _Pragma("unroll") for (int mm = 0; mm < 4; ++mm) { int rl = (mh) * 64 + mm * 16 + (lane & 15); _Pragma("unroll") for (int ks = 0; ks < 2; ++ks) a_frag[mm][ks] = ld_fragA(smem, (buf), wr, rl, ks, lane); } } while (0)
#define RD_B(buf, nh) do { _Pragma("unroll") for (int nn = 0; nn < 2; ++nn) { int cl = (wc & 1) * 64 + (nh) * 32 + nn * 16 + (lane & 15); _Pragma("unroll") for (int ks = 0; ks < 2; ++ks) b_frag[nh][nn][ks] = ld_fragB(smem, (buf), (wc >> 1), cl, ks, lane); } } while (0)
#define MF(mh, nh) do { __builtin_amdgcn_s_setprio(1); _Pragma("unroll") for (int mm = 0; mm < 4; ++mm) _Pragma("unroll") for (int nn = 0; nn < 2; ++nn) _Pragma("unroll") for (int ks = 0; ks < 2; ++ks) acc[(mh) * 4 + mm][(nh) * 2 + nn] = __builtin_amdgcn_mfma_f32_16x16x32_bf16(a_frag[mm][ks], b_frag[(nh)][nn][ks], acc[(mh) * 4 + mm][(nh) * 2 + nn], 0, 0, 0); __builtin_amdgcn_s_setprio(0); } while (0)

  // Prologue: t0 fully + t1's B halves; retire t0 (8 loads), keep B(t1) in flight.
  ST_A(0, 0, 0); ST_A(0, 1, 0); ST_B(0, 0, 0); ST_B(0, 1, 0);
  ST_B(1, 0, 1); ST_B(1, 1, 1);
  VMW(4); BARRIER;

  for (int t0 = 0; t0 + 3 < NKT; t0 += 2) {
    RD_A(0, 0); RD_B(0, 0); ST_A(1, 0, t0 + 1);
    BARRIER; LGKM; MF(0, 0); BARRIER;                  // ph1
    RD_B(0, 1); ST_A(1, 1, t0 + 1);
    BARRIER; LGKM; MF(0, 1); BARRIER;                  // ph2
    RD_A(0, 1); ST_B(0, 0, t0 + 2);
    BARRIER; LGKM; MF(1, 1); BARRIER;                  // ph3
    ST_B(0, 1, t0 + 2); VMW(4);
    BARRIER; LGKM; MF(1, 0); BARRIER;                  // ph4 (t1 landed)
    RD_A(1, 0); RD_B(1, 0); ST_A(0, 0, t0 + 2);
    BARRIER; LGKM; MF(0, 0); BARRIER;                  // ph5
    RD_B(1, 1); ST_A(0, 1, t0 + 2);
    BARRIER; LGKM; MF(0, 1); BARRIER;                  // ph6
    RD_A(1, 1); ST_B(1, 0, t0 + 3);
    BARRIER; LGKM; MF(1, 1); BARRIER;                  // ph7
    ST_B(1, 1, t0 + 3); VMW(4);
    BARRIER; LGKM; MF(1, 0); BARRIER;                  // ph8 (t2 landed)
  }

  // Peeled final pair.
  {
    const int t1 = NKT - 1;
    RD_A(0, 0); RD_B(0, 0); ST_A(1, 0, t1);
    BARRIER; LGKM; MF(0, 0); BARRIER;
    RD_B(0, 1); ST_A(1, 1, t1);
    BARRIER; LGKM; MF(0, 1); BARRIER;
    RD_A(0, 1);
    BARRIER; LGKM; MF(1, 1); BARRIER;
    VMW(0);
    BARRIER; LGKM; MF(1, 0); BARRIER;
    RD_A(1, 0); RD_B(1, 0);
    BARRIER; LGKM; MF(0, 0); BARRIER;
    RD_B(1, 1);
    BARRIER; LGKM; MF(0, 1); BARRIER;
    RD_A(1, 1);
    BARRIER; LGKM; MF(1, 1); BARRIER;
    BARRIER; LGKM; MF(1, 0); BARRIER;
  }

  __syncthreads();   // drain everything before smem reuse

  if constexpr (EPI == 0) {
    // y epilogue: per-wave LDS round-trip -> 256B-contiguous stores + bias.
    float* wlds = (float*)(smem + (unsigned)wid * 16384u);
    const int gcol = ncol0 + wc * 64 + lane;
    const bool cok = (gcol < N);
    const float bv = (bias != nullptr && cok) ? bias[gcol] : 0.f;
#pragma unroll
    for (int mh = 0; mh < 2; ++mh) {
#pragma unroll
      for (int mm = 0; mm < 4; ++mm)
#pragma unroll
        for (int nn = 0; nn < 4; ++nn)
#pragma unroll
          for (int r = 0; r < 4; ++r) {
            int row = mm * 16 + ((lane >> 4) << 2) + r;
            int colv = nn * 16 + (lane & 15);
            int cs = (colv + ((row >> 2) & 3) * 16) & 63;
            wlds[row * 64 + cs] = acc[mh * 4 + mm][nn][r];
          }
#pragma unroll 8
      for (int row = 0; row < 64; ++row) {
        int cs = (lane + ((row >> 2) & 3) * 16) & 63;
        float v = wlds[row * 64 + cs] + bv;
        int grow = mrow0 + wr * 128 + mh * 64 + row;
        if (cok) C[(size_t)grow * N + gcol] = v;
      }
    }
  } else {
    // LSTM epilogue: tile cols = 4 gates x 64 j's (gate-interleaved WgT).
    // Wave wc holds gate wc. Exchange via per-wr [64][256] f32 LDS region.
    float* ep = (float*)(smem + (unsigned)wr * 65536u);
    const int lt = (wid & 3) * 64 + lane;   // 0..255 within wr-group
    const int jj = lt & 63;
    const int rh = lt >> 6;                  // 0..3
    const int gjj = (ncol0 >> 2) + jj;       // global j
    const float bf_ = P.b0[gjj], big_ = P.b1[gjj], bog_ = P.b2[gjj], bi_ = P.b3[gjj];
#pragma unroll
    for (int mh = 0; mh < 2; ++mh) {
#pragma unroll
      for (int mm = 0; mm < 4; ++mm)
#pragma unroll
        for (int nn = 0; nn < 4; ++nn)
#pragma unroll
          for (int r = 0; r < 4; ++r) {
            int row = mm * 16 + ((lane >> 4) << 2) + r;
            int colv = nn * 16 + (lane & 15);
            int cs = (colv + ((row >> 2) & 3) * 16) & 63;
            ep[row * 256 + wc * 64 + cs] = acc[mh * 4 + mm][nn][r];
          }
      __syncthreads();
#pragma unroll
      for (int rr = 0; rr < 16; ++rr) {
        int row = rh * 16 + rr;
        int rot = (jj + ((row >> 2) & 3) * 16) & 63;
        float g0 = ep[row * 256 +   0 + rot];
        float g1 = ep[row * 256 +  64 + rot];
        float g2 = ep[row * 256 + 128 + rot];
        float g3 = ep[row * 256 + 192 + rot];
        int grow = mrow0 + wr * 128 + mh * 64 + row;
        size_t off = (size_t)grow * 2048 + gjj;
        float fg = 1.f / (1.f + expf(-(g0 + bf_)));
        float ig = 1.f / (1.f + expf(-(g1 + big_)));
        float og = 1.f / (1.f + expf(-(g2 + bog_)));
        float gt = tanhf(g3 + bi_);
        float cn = fg * P.c[off] + ig * gt;
        float hn = og * tanhf(cn);
        P.cnew[off] = cn;
        P.hnew[off] = hn;
        P.hnbf[off] = f2bf(hn);
      }
      __syncthreads();
    }
  }
#undef STG
#undef ST_A
#undef ST_B
#undef RD_A
#undef RD_B
#undef MF
}

// ---------------- m97-style 128x128 tail GEMM (N-edge) ----------------
__global__ __launch_bounds__(256) void k_gemm_tail(
    const unsigned short* __restrict__ A, const unsigned short* __restrict__ Bt,
    const float* __restrict__ bias, float* __restrict__ C,
    int N, int K, int lda, int ncol_base) {
  __shared__ unsigned short As[128 * 32];
  __shared__ unsigned short Bs[128 * 32];
  const int tid = threadIdx.x;
  const int lane = tid & 63;
  const int wid = tid >> 6;

  int nwg = gridDim.x * gridDim.y;   // must be % 8 == 0
  int o = blockIdx.y * gridDim.x + blockIdx.x;
  int q = nwg >> 3;
  int s = (o & 7) * q + (o >> 3);
  const int mrow0 = (s / gridDim.x) * 128;
  const int ncol0 = ncol_base + (s % gridDim.x) * 128;

  f32x4 acc[4][4];
#pragma unroll
  for (int m = 0; m < 4; ++m)
#pragma unroll
    for (int n = 0; n < 4; ++n) acc[m][n] = {0.f, 0.f, 0.f, 0.f};

  const int wr = wid >> 1, wc = wid & 1;
  const int brow0 = wr * 64, bcol0 = wc * 64;

  int a_off[4], b_off[4];
#pragma unroll
  for (int m = 0; m < 4; ++m)
    a_off[m] = (brow0 + m * 16 + (lane & 15)) * 32 + ((lane >> 4) << 3);
#pragma unroll
  for (int n = 0; n < 4; ++n)
    b_off[n] = (bcol0 + n * 16 + (lane & 15)) * 32 + ((lane >> 4) << 3);

  for (int k0 = 0; k0 < K; k0 += 32) {
#pragma unroll
    for (int i = 0; i < 2; ++i) {
      int slot = i * 256 + tid;
      int r = slot >> 2, ck = slot & 3;
      unsigned short* la = As + (size_t)(i * 256 + wid * 64) * 8;
      unsigned short* lb = Bs + (size_t)(i * 256 + wid * 64) * 8;
      const unsigned short* ga = A + (size_t)(mrow0 + r) * lda + k0 + ck * 8;
      const unsigned short* gb = Bt + (size_t)(ncol0 + r) * K + k0 + ck * 8;
      __builtin_amdgcn_global_load_lds(
          (const __attribute__((address_space(1))) void*)ga,
          (__attribute__((address_space(3))) void*)la, 16, 0, 0);
      __builtin_amdgcn_global_load_lds(
          (const __attribute__((address_space(1))) void*)gb,
          (__attribute__((address_space(3))) void*)lb, 16, 0, 0);
    }
    __syncthreads();
    short8 af[4], bfr[4];
#pragma unroll
    for (int m = 0; m < 4; ++m) af[m] = *(const short8*)&As[a_off[m]];
#pragma unroll
    for (int n = 0; n < 4; ++n) bfr[n] = *(const short8*)&Bs[b_off[n]];
#pragma unroll
    for (int m = 0; m < 4; ++m)
#pragma unroll
      for (int n = 0; n < 4; ++n)
        acc[m][n] = __builtin_amdgcn_mfma_f32_16x16x32_bf16(af[m], bfr[n], acc[m][n], 0, 0, 0);
    __syncthreads();
  }

#pragma unroll
  for (int n = 0; n < 4; ++n) {
    int col = ncol0 + bcol0 + n * 16 + (lane & 15);
    if (col < N) {
      float bv = bias ? bias[col] : 0.f;
#pragma unroll
      for (int m = 0; m < 4; ++m) {
        int row0 = mrow0 + brow0 + m * 16 + ((lane >> 4) << 2);
        f32x4 v = acc[m][n];
#pragma unroll
        for (int r = 0; r < 4; ++r)
          C[(size_t)(row0 + r) * N + col] = v[r] + bv;
      }
    }
  }
}

extern "C" void kernel_launch(void* const* d_in, const int* in_sizes, int n_in,
                              void* d_out, int out_size, void* d_ws, size_t ws_size,
                              hipStream_t stream) {
  const int B = 2048, F = 2048, Ccls = 50257;
  const int NT = 50304;
  const int*   X    = (const int*)d_in[0];
  const float* h    = (const float*)d_in[1];
  const float* c    = (const float*)d_in[2];
  const float* emb  = (const float*)d_in[3];
  const float* Wf   = (const float*)d_in[4];
  const float* bf   = (const float*)d_in[5];
  const float* Wi   = (const float*)d_in[6];
  const float* bi   = (const float*)d_in[7];
  const float* Wig  = (const float*)d_in[8];
  const float* big  = (const float*)d_in[9];
  const float* Wog  = (const float*)d_in[10];
  const float* bog  = (const float*)d_in[11];
  const float* Wcls = (const float*)d_in[12];
  const float* bcls = (const float*)d_in[13];

  float* y    = (float*)d_out;                 // [B][C]
  float* hnew = y + (size_t)B * Ccls;          // [B][F]
  float* cnew = hnew + (size_t)B * F;          // [B][F]

  // ws: hnbf [0,8.4MB); xh [8.4,25.2); WgT [25.2,92.3); WclsT aliases [8.4,214.4)
  char* ws = (char*)d_ws;
  unsigned short* hnbf  = (unsigned short*)ws;
  unsigned short* xh    = (unsigned short*)(ws + 8388608);
  unsigned short* WgT   = (unsigned short*)(ws + 25165824);
  unsigned short* WclsT = (unsigned short*)(ws + 8388608);

  EpiP pz{nullptr, nullptr, nullptr, nullptr, nullptr, nullptr, nullptr, nullptr};

  // 1) xh = [emb[X], h] -> bf16
  k_build_xh<<<B, 256, 0, stream>>>(X, h, emb, xh);

  // 2) WgT (gate-interleaved, one launch)
  k_cvt_wg<<<dim3(32, 64, 4), 256, 0, stream>>>(Wf, Wig, Wog, Wi, WgT);

  // 3) gates GEMM + fused LSTM epilogue -> hnew, cnew (d_out) + hnbf (ws)
  EpiP pl{c, bf, big, bog, bi, hnew, cnew, hnbf};
  k_gemm256<1><<<dim3(8, 32), 512, 0, stream>>>(
      xh, WgT, nullptr, nullptr, 8192, 4096, 4096, 4096, 8191, pl);

  // 4) WclsT = Wcls^T bf16 [NT rows alloc][2048]
  k_cvt_t<<<dim3(786, 32), 256, 0, stream>>>(Wcls, WclsT, 2048, Ccls, 2048);

  // 5) y main: cols [0, 49152) — 1536 blocks = exactly 6 rounds
  k_gemm256<0><<<dim3(8, 192), 512, 0, stream>>>(
      hnbf, WclsT, bcls, y, Ccls, 2048, 2048, 2048, NT - 1, pz);

  // 6) y tail: cols [49152, 50257) — 9 x 16 = 144 blocks (m97 128^2)
  k_gemm_tail<<<dim3(9, 16), 256, 0, stream>>>(
      hnbf, WclsT, bcls, y, Ccls, 2048, 2048, 49152);
}